// Round 5
// baseline (247.851 us; speedup 1.0000x reference)
//
#include <hip/hip_runtime.h>
#include <hip/hip_cooperative_groups.h>
#include <math.h>

namespace cg = cooperative_groups;

#define NN 8
#define CC 96
#define HH 256
#define WW 256
#define GG 2
#define KK 3
#define CPG (CC / GG)
#define HWD (HH * WW)

typedef float fvec4 __attribute__((ext_vector_type(4)));

// ===========================================================================
// Fused cooperative kernel: 768 blocks x 256 threads, one block per (n,c).
// __launch_bounds__(256, 4): min 4 waves/SIMD -> VGPR<=128 -> >=4 blocks/CU
// capacity, so 768 blocks (3/CU) are guaranteed co-resident.
//
// Phase 1: full-slice sum -> mp[nc] (written every call, no zeroing needed).
// threadfence + grid.sync()
// Phase 2: each block computes its own 3 filter taps (288 FLOP, redundant).
// Phase 3: 3-tap reflect conv + gap + affine epilogue, REVERSE row order so
//          the phase-1 tail is still L2/L3-warm. NT stores keep `out` from
//          evicting x in L3.
// ===========================================================================
__global__ __launch_bounds__(256, 4) void fused_kernel(
    const float* __restrict__ x, const float* __restrict__ Wconv,
    const float* __restrict__ inside_all, const float* __restrict__ lamb_l,
    const float* __restrict__ lamb_h, float* __restrict__ out,
    float* __restrict__ mp) {
    const int nc = blockIdx.x;
    const int t = threadIdx.x;
    const int wave = t >> 6;
    const int lane = t & 63;

    // ---- Phase 1: slice sum (16384 float4 / 256 threads = 64 iters) ----
    const fvec4* xp = (const fvec4*)x + (size_t)nc * (HWD / 4);
    float s = 0.f;
#pragma unroll 8
    for (int i = 0; i < HWD / 4 / 256; ++i) {
        fvec4 v = xp[i * 256 + t];
        s += (v.x + v.y) + (v.z + v.w);
    }
#pragma unroll
    for (int off = 32; off; off >>= 1) s += __shfl_down(s, off, 64);
    __shared__ float ls[4];
    if (lane == 0) ls[wave] = s;
    __syncthreads();
    if (t == 0) mp[nc] = (ls[0] + ls[1]) + (ls[2] + ls[3]);
    __threadfence();  // device-scope: cross-XCD visibility of mp

    cg::this_grid().sync();

    // ---- Phase 2: this block's 3 filter taps ----
    const int c = nc % CC;
    const int n = nc / CC;
    const int g = c / CPG;
    __shared__ float fsh[KK];
    if (t < KK) {
        const float* Wr = Wconv + (g * KK + t) * CC;
        const float* p0 = mp + n * CC;
        float acc = 0.f;
#pragma unroll
        for (int j = 0; j < CC; ++j) acc += p0[j] * Wr[j];
        fsh[t] = tanhf(acc * (1.0f / (float)HWD));
    }
    __syncthreads();
    const float f0 = fsh[0], f1 = fsh[1], f2 = fsh[2];
    const float ia = inside_all[c];
    const float ll = lamb_l[c];
    const float lh1 = lamb_h[c] + 1.0f;
    const float a = ia + 1.0f;

    // ---- Phase 3: conv + gap + epilogue over 256 rows, reverse order ----
    for (int r = HH / 4 - 1; r >= 0; --r) {
        const int row = (r << 2) + wave;
        const size_t base = ((size_t)nc * HH + row) * WW;
        fvec4 v = ((const fvec4*)(x + base))[lane];

        float rs = (v.x + v.y) + (v.z + v.w);
#pragma unroll
        for (int off = 1; off < 64; off <<= 1) rs += __shfl_xor(rs, off, 64);
        const float gap = rs * (1.0f / (float)WW);

        const float left = __shfl_up(v.w, 1, 64);
        const float right = __shfl_down(v.x, 1, 64);
        const float xm1 = (lane == 0) ? v.y : left;    // reflect: x[-1]=x[1]
        const float xp1 = (lane == 63) ? v.z : right;  // reflect: x[W]=x[W-2]

        const float c0 = f0 * xm1 + f1 * v.x + f2 * v.y;
        const float c1 = f0 * v.x + f1 * v.y + f2 * v.z;
        const float c2 = f0 * v.y + f1 * v.z + f2 * v.w;
        const float c3 = f0 * v.z + f1 * v.w + f2 * xp1;

        const float bterm = ia * gap;
        fvec4 o;
        o.x = (c0 * a - bterm) * ll + v.x * lh1;
        o.y = (c1 * a - bterm) * ll + v.y * lh1;
        o.z = (c2 * a - bterm) * ll + v.z * lh1;
        o.w = (c3 * a - bterm) * ll + v.w * lh1;
        __builtin_nontemporal_store(o, (fvec4*)(out + base) + lane);
    }
}

// ===========================================================================
// Fallback path (proven R3 kernels) in case co-residency can't be guaranteed.
// ===========================================================================
__global__ __launch_bounds__(256) void mean_kernel(const float* __restrict__ x,
                                                   float* __restrict__ m) {
    const int b = blockIdx.x;
    const fvec4* xp = (const fvec4*)(x + (size_t)b * HWD);
    const int t = threadIdx.x;
    float s = 0.f;
#pragma unroll 8
    for (int i = 0; i < HWD / 4 / 256; ++i) {
        fvec4 v = xp[i * 256 + t];
        s += (v.x + v.y) + (v.z + v.w);
    }
#pragma unroll
    for (int off = 32; off; off >>= 1) s += __shfl_down(s, off, 64);
    __shared__ float ls[4];
    const int wid = t >> 6;
    if ((t & 63) == 0) ls[wid] = s;
    __syncthreads();
    if (t == 0) m[b] = ((ls[0] + ls[1]) + (ls[2] + ls[3])) * (1.0f / (float)HWD);
}

__global__ void filt_kernel(const float* __restrict__ m,
                            const float* __restrict__ Wconv,
                            float* __restrict__ filt) {
    const int t = threadIdx.x;
    if (t >= NN * GG * KK) return;
    const int n = t / (GG * KK);
    const int gk = t % (GG * KK);
    float s = 0.f;
#pragma unroll
    for (int c = 0; c < CC; ++c) s += m[n * CC + c] * Wconv[gk * CC + c];
    filt[t] = tanhf(s);
}

__global__ __launch_bounds__(256) void main_kernel(
    const float* __restrict__ x, const float* __restrict__ filt,
    const float* __restrict__ inside_all, const float* __restrict__ lamb_l,
    const float* __restrict__ lamb_h, float* __restrict__ out) {
    const int wave = threadIdx.x >> 6;
    const int lane = threadIdx.x & 63;
    const int nc = blockIdx.x >> 6;
    const int row_in_nc = ((blockIdx.x & 63) << 2) + wave;
    const int c = nc % CC;
    const int n = nc / CC;
    const int g = c / CPG;

    const float* fr = filt + (n * GG + g) * KK;
    const float f0 = fr[0], f1 = fr[1], f2 = fr[2];
    const float ia = inside_all[c];
    const float ll = lamb_l[c];
    const float lh1 = lamb_h[c] + 1.0f;

    const size_t base = ((size_t)nc * HH + row_in_nc) * WW;
    fvec4 v = ((const fvec4*)(x + base))[lane];

    float s = (v.x + v.y) + (v.z + v.w);
#pragma unroll
    for (int off = 1; off < 64; off <<= 1) s += __shfl_xor(s, off, 64);
    const float gap = s * (1.0f / (float)WW);

    const float left = __shfl_up(v.w, 1, 64);
    const float right = __shfl_down(v.x, 1, 64);
    const float xm1 = (lane == 0) ? v.y : left;
    const float xp1 = (lane == 63) ? v.z : right;

    const float c0 = f0 * xm1 + f1 * v.x + f2 * v.y;
    const float c1 = f0 * v.x + f1 * v.y + f2 * v.z;
    const float c2 = f0 * v.y + f1 * v.z + f2 * v.w;
    const float c3 = f0 * v.z + f1 * v.w + f2 * xp1;

    const float a = ia + 1.0f;
    const float bterm = ia * gap;

    fvec4 o;
    o.x = (c0 * a - bterm) * ll + v.x * lh1;
    o.y = (c1 * a - bterm) * ll + v.y * lh1;
    o.z = (c2 * a - bterm) * ll + v.z * lh1;
    o.w = (c3 * a - bterm) * ll + v.w * lh1;
    __builtin_nontemporal_store(o, (fvec4*)(out + base) + lane);
}

// ===========================================================================
extern "C" void kernel_launch(void* const* d_in, const int* in_sizes, int n_in,
                              void* d_out, int out_size, void* d_ws,
                              size_t ws_size, hipStream_t stream) {
    const float* x = (const float*)d_in[0];
    const float* Wconv = (const float*)d_in[1];
    const float* inside_all = (const float*)d_in[2];
    const float* lamb_l = (const float*)d_in[3];
    const float* lamb_h = (const float*)d_in[4];
    float* out = (float*)d_out;
    float* mp = (float*)d_ws;  // NN*CC floats (+ filt for fallback)

    // Host-side co-residency check (capture-safe, deterministic).
    int maxblk = 0;
    hipError_t qerr = hipOccupancyMaxActiveBlocksPerMultiprocessor(
        &maxblk, fused_kernel, 256, 0);
    const bool coop_ok = (qerr == hipSuccess) && (maxblk * 256 >= NN * CC);

    if (coop_ok) {
        void* kargs[] = {(void*)&x,      (void*)&Wconv, (void*)&inside_all,
                         (void*)&lamb_l, (void*)&lamb_h, (void*)&out,
                         (void*)&mp};
        hipLaunchCooperativeKernel(fused_kernel, dim3(NN * CC), dim3(256),
                                   kargs, 0, stream);
    } else {
        float* filt = mp + NN * CC;
        mean_kernel<<<NN * CC, 256, 0, stream>>>(x, mp);
        filt_kernel<<<1, 64, 0, stream>>>(mp, Wconv, filt);
        main_kernel<<<(NN * CC * HH) / 4, 256, 0, stream>>>(
            x, filt, inside_all, lamb_l, lamb_h, out);
    }
}

// Round 6
// 93.321 us; speedup vs baseline: 2.6559x; 2.6559x over previous
//
#include <hip/hip_runtime.h>
#include <math.h>

#define NN 8
#define CC 96
#define HH 256
#define WW 256
#define GG 2
#define KK 3
#define CPG (CC / GG)
#define HWD (HH * WW)
#define CHUNKS 8   // mean-pass chunks per (n,c) slice

typedef float fvec4 __attribute__((ext_vector_type(4)));

// ---------------------------------------------------------------------------
// Kernel A: partial sums. 6144 blocks (8 per (n,c) slice), 256 threads.
// Each block sums 8192 floats (2048 float4, 8 per thread, all independent ->
// MLP=8/lane) and writes ONE raw partial to mp[b]. 8 blocks/CU resident.
// Normal loads on purpose: allocate x into L3 for the main pass.
// ---------------------------------------------------------------------------
__global__ __launch_bounds__(256) void partial_kernel(
    const float* __restrict__ x, float* __restrict__ mp) {
    const int b = blockIdx.x;           // 0 .. NN*CC*CHUNKS-1
    const int nc = b >> 3;
    const int chunk = b & 7;
    const int t = threadIdx.x;
    const fvec4* xp = (const fvec4*)x + (size_t)nc * (HWD / 4)
                      + (size_t)chunk * (HWD / 4 / CHUNKS);
    float s = 0.f;
#pragma unroll
    for (int i = 0; i < HWD / 4 / CHUNKS / 256; ++i) {  // 8 iters
        fvec4 v = xp[i * 256 + t];
        s += (v.x + v.y) + (v.z + v.w);
    }
#pragma unroll
    for (int off = 32; off; off >>= 1) s += __shfl_down(s, off, 64);
    __shared__ float ls[4];
    if ((t & 63) == 0) ls[t >> 6] = s;
    __syncthreads();
    if (t == 0) mp[b] = (ls[0] + ls[1]) + (ls[2] + ls[3]);
}

// ---------------------------------------------------------------------------
// Kernel B: main pass. Grid NN*CC*HH/16 = 12288 blocks; each block owns 16
// rows of one (n,c): wave w handles rows rblk*16 + w*4 + {0..3} with 4
// independent load->reduce chains (MLP=4/lane).
// Prologue: rebuild this block's 3 filter taps from the partials (L2
// broadcast reads, ~1 us amortized across resident blocks).
// NT stores keep `out` from evicting x in L3.
// ---------------------------------------------------------------------------
__global__ __launch_bounds__(256) void main_kernel(
    const float* __restrict__ x, const float* __restrict__ mp,
    const float* __restrict__ Wconv, const float* __restrict__ inside_all,
    const float* __restrict__ lamb_l, const float* __restrict__ lamb_h,
    float* __restrict__ out) {
    const int bb = blockIdx.x;
    const int nc = bb >> 4;             // HH/16 = 16 blocks per (n,c)
    const int rblk = bb & 15;
    const int t = threadIdx.x;
    const int wave = t >> 6;
    const int lane = t & 63;
    const int c = nc % CC;
    const int n = nc / CC;
    const int g = c / CPG;

    // ---- Prologue: per-channel mean sums -> LDS, then 3 taps ----
    __shared__ float msh[CC];
    __shared__ float fsh[KK];
    if (t < CC) {
        const float* pr = mp + ((size_t)n * CC + t) * CHUNKS;
        float a0 = 0.f;
#pragma unroll
        for (int k = 0; k < CHUNKS; ++k) a0 += pr[k];
        msh[t] = a0;
    }
    __syncthreads();
    if (t < KK) {
        const float* Wr = Wconv + (g * KK + t) * CC;
        float acc = 0.f;
#pragma unroll
        for (int j = 0; j < CC; ++j) acc += msh[j] * Wr[j];
        fsh[t] = tanhf(acc * (1.0f / (float)HWD));
    }
    __syncthreads();
    const float f0 = fsh[0], f1 = fsh[1], f2 = fsh[2];
    const float ia = inside_all[c];
    const float ll = lamb_l[c];
    const float lh1 = lamb_h[c] + 1.0f;
    const float a = ia + 1.0f;

    // ---- 4 rows per wave, interleaved chains ----
    const int row0 = (rblk << 4) + (wave << 2);
    const size_t base = ((size_t)nc * HH + row0) * WW;
    fvec4 v0 = ((const fvec4*)(x + base + 0 * WW))[lane];
    fvec4 v1 = ((const fvec4*)(x + base + 1 * WW))[lane];
    fvec4 v2 = ((const fvec4*)(x + base + 2 * WW))[lane];
    fvec4 v3 = ((const fvec4*)(x + base + 3 * WW))[lane];

    float s0 = (v0.x + v0.y) + (v0.z + v0.w);
    float s1 = (v1.x + v1.y) + (v1.z + v1.w);
    float s2 = (v2.x + v2.y) + (v2.z + v2.w);
    float s3 = (v3.x + v3.y) + (v3.z + v3.w);
#pragma unroll
    for (int off = 1; off < 64; off <<= 1) {
        s0 += __shfl_xor(s0, off, 64);
        s1 += __shfl_xor(s1, off, 64);
        s2 += __shfl_xor(s2, off, 64);
        s3 += __shfl_xor(s3, off, 64);
    }

#pragma unroll
    for (int r = 0; r < 4; ++r) {
        const fvec4 v = (r == 0) ? v0 : (r == 1) ? v1 : (r == 2) ? v2 : v3;
        const float rs = (r == 0) ? s0 : (r == 1) ? s1 : (r == 2) ? s2 : s3;
        const float gap = rs * (1.0f / (float)WW);

        const float left = __shfl_up(v.w, 1, 64);
        const float right = __shfl_down(v.x, 1, 64);
        const float xm1 = (lane == 0) ? v.y : left;    // reflect: x[-1]=x[1]
        const float xp1 = (lane == 63) ? v.z : right;  // reflect: x[W]=x[W-2]

        const float c0 = f0 * xm1 + f1 * v.x + f2 * v.y;
        const float c1 = f0 * v.x + f1 * v.y + f2 * v.z;
        const float c2 = f0 * v.y + f1 * v.z + f2 * v.w;
        const float c3 = f0 * v.z + f1 * v.w + f2 * xp1;

        const float bterm = ia * gap;
        fvec4 o;
        o.x = (c0 * a - bterm) * ll + v.x * lh1;
        o.y = (c1 * a - bterm) * ll + v.y * lh1;
        o.z = (c2 * a - bterm) * ll + v.z * lh1;
        o.w = (c3 * a - bterm) * ll + v.w * lh1;
        __builtin_nontemporal_store(o, (fvec4*)(out + base + r * WW) + lane);
    }
}

// ---------------------------------------------------------------------------
extern "C" void kernel_launch(void* const* d_in, const int* in_sizes, int n_in,
                              void* d_out, int out_size, void* d_ws,
                              size_t ws_size, hipStream_t stream) {
    const float* x = (const float*)d_in[0];
    const float* Wconv = (const float*)d_in[1];
    const float* inside_all = (const float*)d_in[2];
    const float* lamb_l = (const float*)d_in[3];
    const float* lamb_h = (const float*)d_in[4];
    float* out = (float*)d_out;
    float* mp = (float*)d_ws;  // NN*CC*CHUNKS raw partial sums

    partial_kernel<<<NN * CC * CHUNKS, 256, 0, stream>>>(x, mp);
    main_kernel<<<NN * CC * (HH / 16), 256, 0, stream>>>(
        x, mp, Wconv, inside_all, lamb_l, lamb_h, out);
}